// Round 6
// baseline (13261.247 us; speedup 1.0000x reference)
//
#include <hip/hip_runtime.h>
#include <hip/hip_bf16.h>
#include <math.h>

typedef __bf16 bf16;
typedef __bf16 bf16x8 __attribute__((ext_vector_type(8)));
typedef float f32x16 __attribute__((ext_vector_type(16)));

#define T_STEPS 512
#define BATCH   128
#define DIN     512
#define HID     1024
#define G4      4096
#define DOUT    512

__device__ __forceinline__ float sigm(float x){ return 1.0f / (1.0f + __expf(-x)); }

// Staged "A" layout within one K-step (32 k) of a [128 x K] activation matrix:
// [kstep][ks2=2][mf=4][kg=2][row=32][8elems]  (4096 elems per kstep)
__device__ __forceinline__ int zoff(int b, int k){
    return (k >> 5) * 4096 + ((k >> 4) & 1) * 2048 + (b >> 5) * 512 +
           ((k >> 3) & 1) * 256 + (b & 31) * 8 + (k & 7);
}

#define GLOAD_LDS(gsrc, ldsdst) \
  __builtin_amdgcn_global_load_lds((const __attribute__((address_space(1))) void*)(gsrc), \
                                   (__attribute__((address_space(3))) void*)(ldsdst), 16, 0, 0)

// ---------------- prep kernels ----------------

// W row-major [4096][K] fp32 -> staged bf16 hi/lo, 128-col ntiles:
// [ntile=32][kstep=K/32][ks2=2][cg=4][kg=2][col=32][8]  (4096 elems per (ntile,kstep))
__global__ void wstage(const float* __restrict__ src, bf16* __restrict__ hi,
                       bf16* __restrict__ lo, int lk){
    int i = blockIdx.x * 256 + threadIdx.x;
    int K = 1 << lk;
    int n = i >> lk, k = i & (K - 1);
    float v = src[i];
    bf16 h = (bf16)v;
    int off = ((n >> 7) * (K >> 5) + (k >> 5)) * 4096 + ((k >> 4) & 1) * 2048 +
              ((n >> 5) & 3) * 512 + ((k >> 3) & 1) * 256 + (n & 31) * 8 + (k & 7);
    hi[off] = h;
    lo[off] = (bf16)(v - (float)h);
}

// x [B][T][D] fp32 -> staged [T][zoff(b,d)] bf16 hi/lo
__global__ void xstage(const float* __restrict__ x, bf16* __restrict__ hi,
                       bf16* __restrict__ lo){
    int i = blockIdx.x * 256 + threadIdx.x;       // T*B*D = 2^25
    int d = i & 511;
    int b = (i >> 9) & 127;
    int t = i >> 16;
    float v = x[((size_t)b * T_STEPS + t) * DIN + d];
    bf16 h = (bf16)v;
    size_t off = (size_t)t * 65536 + zoff(b, d);
    hi[off] = h;
    lo[off] = (bf16)(v - (float)h);
}

__global__ void bias_kernel(const float* __restrict__ bih1, const float* __restrict__ bhh1,
                            const float* __restrict__ bih2, const float* __restrict__ bhh2,
                            float* __restrict__ bias1, float* __restrict__ bias2){
    int i = blockIdx.x * 256 + threadIdx.x;
    if (i < G4){
        bias1[i] = bih1[i] + bhh1[i];
        bias2[i] = bih2[i] + bhh2[i];
    }
}

// ---------------- per-step GEMM ----------------
// 224 blocks x 256 threads. Block = group g (7 K-shards) x ntile (32 x 128-col tiles).
// Block tile: 128(M) x 128(N) x 512(K); 4 waves each 64x64 via mfma_f32_32x32x16_bf16.
// 3-term split: w_hi*a_hi + w_lo*a_hi + w_hi*a_lo -> fp32 gpart[7][128][4096].
__global__ __launch_bounds__(256)
void gemm_step(const bf16* __restrict__ x_h,  const bf16* __restrict__ x_l,
               const bf16* __restrict__ h1_h, const bf16* __restrict__ h1_l,
               const bf16* __restrict__ h2_h, const bf16* __restrict__ h2_l,
               const bf16* __restrict__ w1x_h, const bf16* __restrict__ w1x_l,
               const bf16* __restrict__ w1h_h, const bf16* __restrict__ w1h_l,
               const bf16* __restrict__ w2i_h, const bf16* __restrict__ w2i_l,
               const bf16* __restrict__ w2h_h, const bf16* __restrict__ w2h_l,
               float* __restrict__ gpart, int t)
{
    int g     = blockIdx.x >> 5;
    int ntile = blockIdx.x & 31;
    if (t == T_STEPS && g < 3) return;   // last round: layer2 only
    if (t == 0 && g >= 3)      return;   // first round: layer1 only
    int p1 = (t - 1) & 1, p2 = t & 1;

    const bf16 *Ah, *Al, *Wh, *Wl;
    int kstep0, wks;
    switch (g){
      case 0: Ah = x_h + (size_t)t * 65536; Al = x_l + (size_t)t * 65536;
              Wh = w1x_h; Wl = w1x_l; kstep0 = 0;  wks = 16; break;
      case 1: Ah = h1_h + p1 * 131072; Al = h1_l + p1 * 131072;
              Wh = w1h_h; Wl = w1h_l; kstep0 = 0;  wks = 32; break;
      case 2: Ah = h1_h + p1 * 131072; Al = h1_l + p1 * 131072;
              Wh = w1h_h; Wl = w1h_l; kstep0 = 16; wks = 32; break;
      case 3: Ah = h1_h + p1 * 131072; Al = h1_l + p1 * 131072;
              Wh = w2i_h; Wl = w2i_l; kstep0 = 0;  wks = 32; break;
      case 4: Ah = h1_h + p1 * 131072; Al = h1_l + p1 * 131072;
              Wh = w2i_h; Wl = w2i_l; kstep0 = 16; wks = 32; break;
      case 5: Ah = h2_h + p2 * 131072; Al = h2_l + p2 * 131072;
              Wh = w2h_h; Wl = w2h_l; kstep0 = 0;  wks = 32; break;
      default: Ah = h2_h + p2 * 131072; Al = h2_l + p2 * 131072;
              Wh = w2h_h; Wl = w2h_l; kstep0 = 16; wks = 32; break;
    }

    __shared__ __align__(1024) char smem[65536];   // 2 buffers x 32 KB
    int wave = threadIdx.x >> 6, lane = threadIdx.x & 63;
    int wm = wave >> 1, wn = wave & 1;
    int laneoff = ((lane >> 5) << 9) + ((lane & 31) << 4);

    auto stage = [&](int buf, int s){
        int ks = kstep0 + s;
        const bf16* Ash = Ah + (size_t)ks * 4096;
        const bf16* Asl = Al + (size_t)ks * 4096;
        const bf16* Wsh = Wh + ((size_t)ntile * wks + ks) * 4096;
        const bf16* Wsl = Wl + ((size_t)ntile * wks + ks) * 4096;
        char* base = smem + buf * 32768;
        #pragma unroll
        for (int c = 0; c < 2; ++c){
            int ii = wave * 2 + c;
            GLOAD_LDS(Ash + ii * 512 + lane * 8, base          + ii * 1024);
            GLOAD_LDS(Asl + ii * 512 + lane * 8, base + 8192   + ii * 1024);
            GLOAD_LDS(Wsh + ii * 512 + lane * 8, base + 16384  + ii * 1024);
            GLOAD_LDS(Wsl + ii * 512 + lane * 8, base + 24576  + ii * 1024);
        }
    };

    f32x16 a00 = {0,0,0,0,0,0,0,0,0,0,0,0,0,0,0,0};
    f32x16 a01 = a00, a10 = a00, a11 = a00;

    stage(0, 0);
    __syncthreads();
    for (int s = 0; s < 16; ++s){
        if (s < 15) stage((s + 1) & 1, s + 1);
        const char* b = smem + (s & 1) * 32768;
        #pragma unroll
        for (int k2 = 0; k2 < 2; ++k2){
            bf16x8 ah0 = *(const bf16x8*)(b + k2*4096 + (wm*2    )*1024 + laneoff);
            bf16x8 ah1 = *(const bf16x8*)(b + k2*4096 + (wm*2 + 1)*1024 + laneoff);
            bf16x8 al0 = *(const bf16x8*)(b + 8192  + k2*4096 + (wm*2    )*1024 + laneoff);
            bf16x8 al1 = *(const bf16x8*)(b + 8192  + k2*4096 + (wm*2 + 1)*1024 + laneoff);
            bf16x8 wh0 = *(const bf16x8*)(b + 16384 + k2*4096 + (wn*2    )*1024 + laneoff);
            bf16x8 wh1 = *(const bf16x8*)(b + 16384 + k2*4096 + (wn*2 + 1)*1024 + laneoff);
            bf16x8 wl0 = *(const bf16x8*)(b + 24576 + k2*4096 + (wn*2    )*1024 + laneoff);
            bf16x8 wl1 = *(const bf16x8*)(b + 24576 + k2*4096 + (wn*2 + 1)*1024 + laneoff);
            a00 = __builtin_amdgcn_mfma_f32_32x32x16_bf16(ah0, wh0, a00, 0, 0, 0);
            a01 = __builtin_amdgcn_mfma_f32_32x32x16_bf16(ah0, wh1, a01, 0, 0, 0);
            a10 = __builtin_amdgcn_mfma_f32_32x32x16_bf16(ah1, wh0, a10, 0, 0, 0);
            a11 = __builtin_amdgcn_mfma_f32_32x32x16_bf16(ah1, wh1, a11, 0, 0, 0);
            a00 = __builtin_amdgcn_mfma_f32_32x32x16_bf16(ah0, wl0, a00, 0, 0, 0);
            a01 = __builtin_amdgcn_mfma_f32_32x32x16_bf16(ah0, wl1, a01, 0, 0, 0);
            a10 = __builtin_amdgcn_mfma_f32_32x32x16_bf16(ah1, wl0, a10, 0, 0, 0);
            a11 = __builtin_amdgcn_mfma_f32_32x32x16_bf16(ah1, wl1, a11, 0, 0, 0);
            a00 = __builtin_amdgcn_mfma_f32_32x32x16_bf16(al0, wh0, a00, 0, 0, 0);
            a01 = __builtin_amdgcn_mfma_f32_32x32x16_bf16(al0, wh1, a01, 0, 0, 0);
            a10 = __builtin_amdgcn_mfma_f32_32x32x16_bf16(al1, wh0, a10, 0, 0, 0);
            a11 = __builtin_amdgcn_mfma_f32_32x32x16_bf16(al1, wh1, a11, 0, 0, 0);
        }
        __syncthreads();
    }

    float* gp = gpart + (size_t)g * (BATCH * G4);
    int col0 = ntile * 128 + (wn * 2    ) * 32 + (lane & 31);
    int col1 = ntile * 128 + (wn * 2 + 1) * 32 + (lane & 31);
    #pragma unroll
    for (int r = 0; r < 16; ++r){
        int row32 = (r & 3) + 8 * (r >> 2) + 4 * (lane >> 5);
        gp[(size_t)(wm * 64 + row32) * G4 + col0]      = a00[r];
        gp[(size_t)(wm * 64 + row32) * G4 + col1]      = a01[r];
        gp[(size_t)(wm * 64 + 32 + row32) * G4 + col0] = a10[r];
        gp[(size_t)(wm * 64 + 32 + row32) * G4 + col1] = a11[r];
    }
}

// ---------------- per-step cell update ----------------
__global__ __launch_bounds__(256)
void cell_step(const float* __restrict__ gpart,
               const float* __restrict__ bias1, const float* __restrict__ bias2,
               float* __restrict__ c1, float* __restrict__ c2,
               bf16* __restrict__ h1_h, bf16* __restrict__ h1_l,
               bf16* __restrict__ h2_h, bf16* __restrict__ h2_l,
               float* __restrict__ h2t, int t)
{
    int tid = blockIdx.x * 256 + threadIdx.x;   // 256*256 = 65536 threads
    for (int L = 0; L < 2; ++L){
        if (L == 0 && t == T_STEPS) continue;
        if (L == 1 && t == 0)       continue;
        int s = L ? (t - 1) : t;
        int p = s & 1;
        const float* bias = L ? bias2 : bias1;
        float* c  = L ? c2 : c1;
        bf16* hh = (L ? h2_h : h1_h) + p * 131072;
        bf16* hl = (L ? h2_l : h1_l) + p * 131072;
        int sh0 = L ? 3 : 0;
        int nsh = L ? 4 : 3;
        for (int it = tid; it < BATCH * HID; it += 65536){
            int b = it >> 10;
            int j = it & (HID - 1);
            size_t base = (size_t)b * G4 + j;
            float g4[4];
            #pragma unroll
            for (int q = 0; q < 4; ++q){
                float v = bias[j + q * 1024];
                for (int sh = 0; sh < nsh; ++sh)
                    v += gpart[(size_t)(sh0 + sh) * (BATCH * G4) + base + q * 1024];
                g4[q] = v;
            }
            float iv = sigm(g4[0]), fv = sigm(g4[1]), gv = tanhf(g4[2]), ov = sigm(g4[3]);
            float cn = fv * c[it] + iv * gv;
            c[it] = cn;
            float h = ov * tanhf(cn);
            bf16 hb = (bf16)h;
            int off = zoff(b, j);
            hh[off] = hb;
            hl[off] = (bf16)(h - (float)hb);
            if (L == 1 && s == T_STEPS - 1) h2t[(size_t)j * BATCH + b] = h;
        }
    }
}

// ---------------- output projection (fp32, one-time) ----------------
__global__ __launch_bounds__(128)
void outproj(const float* __restrict__ h2t, const float* __restrict__ wout,
             const float* __restrict__ bout, float* __restrict__ out){
    int o = blockIdx.x;      // 512 blocks
    int b = threadIdx.x;     // 128 threads
    float acc = bout[o];
    const float* wr = wout + (size_t)o * HID;
    for (int k = 0; k < HID; ++k)
        acc += wr[k] * h2t[(size_t)k * BATCH + b];
    out[(size_t)b * DOUT + o] = acc;
}

// ---------------- host launch ----------------
extern "C" void kernel_launch(void* const* d_in, const int* in_sizes, int n_in,
                              void* d_out, int out_size, void* d_ws, size_t ws_size,
                              hipStream_t stream)
{
    const float* x    = (const float*)d_in[0];
    const float* wih1 = (const float*)d_in[1];
    const float* whh1 = (const float*)d_in[2];
    const float* bih1 = (const float*)d_in[3];
    const float* bhh1 = (const float*)d_in[4];
    const float* wih2 = (const float*)d_in[5];
    const float* whh2 = (const float*)d_in[6];
    const float* bih2 = (const float*)d_in[7];
    const float* bhh2 = (const float*)d_in[8];
    const float* wout = (const float*)d_in[9];
    const float* bout = (const float*)d_in[10];
    float* out = (float*)d_out;

    char* p = (char*)d_ws;
    auto alloc = [&](size_t bytes) -> char* {
        char* r = p;
        p += (bytes + 1023) & ~(size_t)1023;
        return r;
    };

    bf16* x_h   = (bf16*)alloc((size_t)T_STEPS * 65536 * 2);
    bf16* x_l   = (bf16*)alloc((size_t)T_STEPS * 65536 * 2);
    bf16* w1x_h = (bf16*)alloc((size_t)G4 * DIN * 2);
    bf16* w1x_l = (bf16*)alloc((size_t)G4 * DIN * 2);
    bf16* w1h_h = (bf16*)alloc((size_t)G4 * HID * 2);
    bf16* w1h_l = (bf16*)alloc((size_t)G4 * HID * 2);
    bf16* w2i_h = (bf16*)alloc((size_t)G4 * HID * 2);
    bf16* w2i_l = (bf16*)alloc((size_t)G4 * HID * 2);
    bf16* w2h_h = (bf16*)alloc((size_t)G4 * HID * 2);
    bf16* w2h_l = (bf16*)alloc((size_t)G4 * HID * 2);
    float* bias1 = (float*)alloc(G4 * 4);
    float* bias2 = (float*)alloc(G4 * 4);
    char* zbase = p;                                   // zeroed block:
    bf16* h1_h = (bf16*)alloc((size_t)2 * 131072 * 2); // staged h parity buffers
    bf16* h1_l = (bf16*)alloc((size_t)2 * 131072 * 2);
    bf16* h2_h = (bf16*)alloc((size_t)2 * 131072 * 2);
    bf16* h2_l = (bf16*)alloc((size_t)2 * 131072 * 2);
    float* c1  = (float*)alloc((size_t)BATCH * HID * 4);
    float* c2  = (float*)alloc((size_t)BATCH * HID * 4);
    size_t zbytes = (size_t)(p - zbase);
    float* gpart = (float*)alloc((size_t)7 * BATCH * G4 * 4);
    float* h2t   = (float*)alloc((size_t)HID * BATCH * 4);
    (void)ws_size; (void)in_sizes; (void)n_in; (void)out_size;

    // prep
    wstage<<<(G4 * DIN) / 256, 256, 0, stream>>>(wih1, w1x_h, w1x_l, 9);
    wstage<<<(G4 * HID) / 256, 256, 0, stream>>>(whh1, w1h_h, w1h_l, 10);
    wstage<<<(G4 * HID) / 256, 256, 0, stream>>>(wih2, w2i_h, w2i_l, 10);
    wstage<<<(G4 * HID) / 256, 256, 0, stream>>>(whh2, w2h_h, w2h_l, 10);
    bias_kernel<<<(G4 + 255) / 256, 256, 0, stream>>>(bih1, bhh1, bih2, bhh2, bias1, bias2);
    xstage<<<(T_STEPS * BATCH * DIN) / 256, 256, 0, stream>>>(x, x_h, x_l);
    hipMemsetAsync(zbase, 0, zbytes, stream);

    // 513 pipelined rounds: round t = layer1(t) + layer2(t-1)
    for (int t = 0; t <= T_STEPS; ++t){
        gemm_step<<<224, 256, 0, stream>>>(x_h, x_l, h1_h, h1_l, h2_h, h2_l,
                                           w1x_h, w1x_l, w1h_h, w1h_l,
                                           w2i_h, w2i_l, w2h_h, w2h_l, gpart, t);
        cell_step<<<256, 256, 0, stream>>>(gpart, bias1, bias2, c1, c2,
                                           h1_h, h1_l, h2_h, h2_l, h2t, t);
    }

    outproj<<<DOUT, BATCH, 0, stream>>>(h2t, wout, bout, out);
}